// Round 11
// baseline (327.471 us; speedup 1.0000x reference)
//
#include <hip/hip_runtime.h>
#include <math.h>

typedef unsigned short ushort_t;
typedef __attribute__((ext_vector_type(8))) short bf16x8;
typedef __attribute__((ext_vector_type(4))) float f32x4;
typedef __attribute__((ext_vector_type(4))) unsigned short us4;
typedef __attribute__((ext_vector_type(8))) unsigned short us8;

#define B_   4
#define S_   512
#define D_   4096
#define H_   32
#define G_   8
#define HD_  128
#define KV_  1024
#define M_   (B_ * S_)   // 2048
#define QN_  6144        // fused QKV column count

__device__ __forceinline__ float bf2f(ushort_t u) {
    union { unsigned u; float f; } x; x.u = ((unsigned)u) << 16; return x.f;
}
__device__ __forceinline__ ushort_t f2bf(float f) {
    union { float f; unsigned u; } x; x.f = f;
    unsigned r = x.u + 0x7fffu + ((x.u >> 16) & 1u);   // round-to-nearest-even
    return (ushort_t)(r >> 16);
}

typedef const __attribute__((address_space(1))) void* gptr_t;
typedef __attribute__((address_space(3))) void* ldsptr_t;

__device__ __forceinline__ void gload_lds16(const void* g, void* lds) {
    __builtin_amdgcn_global_load_lds((gptr_t)g, (ldsptr_t)lds, 16, 0, 0);
}

#define BAR() asm volatile("s_barrier" ::: "memory")

// ---------------- fp32 -> bf16 elementwise ----------------
__global__ void xconv(const float* __restrict__ x, ushort_t* __restrict__ xb, int n8)
{
    const int i = blockIdx.x * blockDim.x + threadIdx.x;
    if (i >= n8) return;
    const float4 a = *(const float4*)&x[(size_t)i * 8];
    const float4 b = *(const float4*)&x[(size_t)i * 8 + 4];
    us8 o;
    o[0] = f2bf(a.x); o[1] = f2bf(a.y); o[2] = f2bf(a.z); o[3] = f2bf(a.w);
    o[4] = f2bf(b.x); o[5] = f2bf(b.y); o[6] = f2bf(b.z); o[7] = f2bf(b.w);
    *(us8*)&xb[(size_t)i * 8] = o;
}

// ------- fused W transpose: {wq|wk|wv} [4096][N] fp32 -> Wt [6144][4096] bf16 -------
__global__ __launch_bounds__(256) void wconv_all(
    const float* __restrict__ wq, const float* __restrict__ wk,
    const float* __restrict__ wv, ushort_t* __restrict__ Wt)
{
    __shared__ float t[32][33];
    const int n0 = blockIdx.x * 32, k0 = blockIdx.y * 32;
    const float* W; int nsrc, N;
    if (n0 < 4096)      { W = wq; nsrc = n0;        N = 4096; }
    else if (n0 < 5120) { W = wk; nsrc = n0 - 4096; N = 1024; }
    else                { W = wv; nsrc = n0 - 5120; N = 1024; }
    const int tid = threadIdx.x;
    const int r = tid >> 3, c4 = (tid & 7) * 4;
    const float4 v = *(const float4*)&W[(size_t)(k0 + r) * N + nsrc + c4];
    t[r][c4 + 0] = v.x; t[r][c4 + 1] = v.y; t[r][c4 + 2] = v.z; t[r][c4 + 3] = v.w;
    __syncthreads();
    us4 o;
    o.x = f2bf(t[c4 + 0][r]);
    o.y = f2bf(t[c4 + 1][r]);
    o.z = f2bf(t[c4 + 2][r]);
    o.w = f2bf(t[c4 + 3][r]);
    *(us4*)&Wt[(size_t)(n0 + r) * D_ + k0 + c4] = o;
}

// ---------------- W [K][N] fp32 -> Wt [N][K] bf16 (single, for wo) ----------------
__global__ __launch_bounds__(256) void wconv(
    const float* __restrict__ W, ushort_t* __restrict__ Wt, int K, int N)
{
    __shared__ float t[32][33];
    const int n0 = blockIdx.x * 32, k0 = blockIdx.y * 32;
    const int tid = threadIdx.x;
    const int r = tid >> 3, c4 = (tid & 7) * 4;
    const float4 v = *(const float4*)&W[(size_t)(k0 + r) * N + n0 + c4];
    t[r][c4 + 0] = v.x; t[r][c4 + 1] = v.y; t[r][c4 + 2] = v.z; t[r][c4 + 3] = v.w;
    __syncthreads();
    us4 o;
    o.x = f2bf(t[c4 + 0][r]);
    o.y = f2bf(t[c4 + 1][r]);
    o.z = f2bf(t[c4 + 2][r]);
    o.w = f2bf(t[c4 + 3][r]);
    *(us4*)&Wt[(size_t)(n0 + r) * K + k0 + c4] = o;
}

// ============ 256x256 8-phase MFMA GEMM (T1+T2+T3+T4+T5) ============
// C[M,N] = A[M,K] @ Bt[N,K]^T + bias.  BK=64, 8 waves (2M x 4N).
// This round: staging addresses PRECOMPUTED per-thread (8 pointers, advance
// t*64 elems -> 1 v_lshl_add per gload) and the K-loop is unrolled x2 with
// the LDS buffer index c passed as a per-copy literal -> all LDS offsets
// fold to immediates.  Sync structure identical to the proven round-8 form.
template<int OUT_BF16, int SPLITK, int ROPE>
__global__ __launch_bounds__(512, 2) void gemm8(
    const ushort_t* __restrict__ A, int lda,
    const ushort_t* __restrict__ Bt, int ldb,
    const float* __restrict__ bias0, const float* __restrict__ bias1,
    const float* __restrict__ bias2,
    float* __restrict__ Cf, ushort_t* __restrict__ Cb,
    float* __restrict__ P0, float* __restrict__ P1,
    int M, int N, int K)
{
    __shared__ ushort_t sA[2][256 * 64];   // 64 KiB
    __shared__ ushort_t sB[2][256 * 64];   // 64 KiB

    const int tid = threadIdx.x;
    const int lane = tid & 63, w = tid >> 6;
    const int lr = lane & 15, kg = lane >> 4;
    const int wr = w >> 2, wc = w & 3;

    // T1: XCD-aware swizzle (grids here are multiples of 8)
    const int nwg = gridDim.x;
    const int cpx = nwg >> 3;
    const int bid = (blockIdx.x & 7) * cpx + (blockIdx.x >> 3);
    int khalf = 0, tile = bid;
    if (SPLITK) { khalf = bid >> 7; tile = bid & 127; }
    const int nbx = N >> 8;
    const int bx = tile % nbx, by = tile / nbx;
    const int bm0 = by << 8, bn0 = bx << 8;
    if (SPLITK) { A += (size_t)khalf * K; Bt += (size_t)khalf * K; }

    const int NT = K >> 6;

    // Precomputed staging pointers: half h (0=A-lo 1=A-hi 2=B-lo 3=B-hi), j=0,1
    const ushort_t* gp[4][2];
    char*           lp[4][2];
    #pragma unroll
    for (int h = 0; h < 4; ++h) {
        const ushort_t* gb; int ld; char* sbase;
        if (h < 2) { gb = A + (size_t)bm0 * lda; ld = lda; sbase = (char*)sA; }
        else       { gb = Bt + (size_t)bn0 * ldb; ld = ldb; sbase = (char*)sB; }
        const int half = h & 1;
        #pragma unroll
        for (int j = 0; j < 2; ++j) {
            const int o = j * 8192 + tid * 16;       // byte within 16KB half
            const int row = half * 128 + (o >> 7);   // tile row
            const int slot = (o >> 4) & 7;
            gp[h][j] = gb + (size_t)row * ld + ((slot ^ (row & 7)) << 3);
            lp[h][j] = sbase + half * 16384 + j * 8192 + w * 1024;
        }
    }
    auto stage = [&](int t, int h, int c) {
        #pragma unroll
        for (int j = 0; j < 2; ++j)
            gload_lds16(gp[h][j] + t * 64, lp[h][j] + c * 32768);
    };
    auto lda_frag = [&](int c, int mi, int s) {
        const int row = mi * 32 + wr * 16 + lr;
        return *(const bf16x8*)((const char*)sA + c * 32768 + row * 128 +
                                (((s * 4 + kg) ^ (row & 7)) << 4));
    };
    auto ldb_frag = [&](int c, int ni, int s) {
        const int row = ni * 64 + wc * 16 + lr;
        return *(const bf16x8*)((const char*)sB + c * 32768 + row * 128 +
                                (((s * 4 + kg) ^ (row & 7)) << 4));
    };

    f32x4 acc[8][4];
    #pragma unroll
    for (int i = 0; i < 8; ++i)
        #pragma unroll
        for (int j = 0; j < 4; ++j)
            acc[i][j] = (f32x4){0.f, 0.f, 0.f, 0.f};

    // prologue: 7 halves in flight, confirm tile 0 (vmcnt 6 = 3 halves out)
    stage(0, 0, 0); stage(0, 2, 0); stage(0, 3, 0); stage(0, 1, 0);
    stage(1, 0, 1); stage(1, 2, 1); stage(1, 3, 1);
    asm volatile("s_waitcnt vmcnt(6)" ::: "memory");
    BAR();

    auto iter = [&](int t, int c) {
        bf16x8 a[4][2], b[4][2];

        // ---- P1: quad (0,0): A-lo x B-lo ----
        #pragma unroll
        for (int ni = 0; ni < 2; ++ni)
            #pragma unroll
            for (int s = 0; s < 2; ++s) b[ni][s] = ldb_frag(c, ni, s);
        #pragma unroll
        for (int mi = 0; mi < 4; ++mi)
            #pragma unroll
            for (int s = 0; s < 2; ++s) a[mi][s] = lda_frag(c, mi, s);
        if (t + 1 < NT) stage(t + 1, 1, c ^ 1);
        BAR();
        __builtin_amdgcn_s_setprio(1);
        #pragma unroll
        for (int mi = 0; mi < 4; ++mi)
            #pragma unroll
            for (int ni = 0; ni < 2; ++ni)
                #pragma unroll
                for (int s = 0; s < 2; ++s)
                    acc[mi][ni] = __builtin_amdgcn_mfma_f32_16x16x32_bf16(
                        a[mi][s], b[ni][s], acc[mi][ni], 0, 0, 0);
        __builtin_amdgcn_s_setprio(0);
        BAR();

        // ---- P2: quad (0,1): A-lo x B-hi ----
        #pragma unroll
        for (int ni = 2; ni < 4; ++ni)
            #pragma unroll
            for (int s = 0; s < 2; ++s) b[ni][s] = ldb_frag(c, ni, s);
        if (t + 2 < NT) stage(t + 2, 0, c);
        BAR();
        __builtin_amdgcn_s_setprio(1);
        #pragma unroll
        for (int mi = 0; mi < 4; ++mi)
            #pragma unroll
            for (int ni = 2; ni < 4; ++ni)
                #pragma unroll
                for (int s = 0; s < 2; ++s)
                    acc[mi][ni] = __builtin_amdgcn_mfma_f32_16x16x32_bf16(
                        a[mi][s], b[ni][s], acc[mi][ni], 0, 0, 0);
        __builtin_amdgcn_s_setprio(0);
        BAR();

        // ---- P3: quad (1,1): A-hi x B-hi ----
        #pragma unroll
        for (int mi = 0; mi < 4; ++mi)
            #pragma unroll
            for (int s = 0; s < 2; ++s) a[mi][s] = lda_frag(c, mi + 4, s);
        if (t + 2 < NT) stage(t + 2, 2, c);
        BAR();
        __builtin_amdgcn_s_setprio(1);
        #pragma unroll
        for (int mi = 0; mi < 4; ++mi)
            #pragma unroll
            for (int ni = 2; ni < 4; ++ni)
                #pragma unroll
                for (int s = 0; s < 2; ++s)
                    acc[mi + 4][ni] = __builtin_amdgcn_mfma_f32_16x16x32_bf16(
                        a[mi][s], b[ni][s], acc[mi + 4][ni], 0, 0, 0);
        __builtin_amdgcn_s_setprio(0);
        BAR();

        // ---- P4: quad (1,0): A-hi x B-lo ----
        if (t + 2 < NT) {
            stage(t + 2, 3, c);
            asm volatile("s_waitcnt vmcnt(6)" ::: "memory");
        } else {
            asm volatile("s_waitcnt vmcnt(0)" ::: "memory");
        }
        BAR();
        __builtin_amdgcn_s_setprio(1);
        #pragma unroll
        for (int mi = 0; mi < 4; ++mi)
            #pragma unroll
            for (int ni = 0; ni < 2; ++ni)
                #pragma unroll
                for (int s = 0; s < 2; ++s)
                    acc[mi + 4][ni] = __builtin_amdgcn_mfma_f32_16x16x32_bf16(
                        a[mi][s], b[ni][s], acc[mi + 4][ni], 0, 0, 0);
        __builtin_amdgcn_s_setprio(0);
        BAR();
    };

    for (int t = 0; t < NT; t += 2) { iter(t, 0); iter(t + 1, 1); }

    // ---- epilogue ----
    if (ROPE && bn0 < 5120) {
        const float scale = (bn0 < 4096) ? (1.f / 128.f) : 1.f;
        const int jj = wc * 16 + lr;                                 // n & 63
        const float invf = __expf(-0.1439115683121279f * (float)jj); // 10000^(-jj/64)
        #pragma unroll
        for (int mi = 0; mi < 8; ++mi) {
            const int mr = bm0 + mi * 32 + wr * 16 + kg * 4;
            #pragma unroll
            for (int r = 0; r < 4; ++r) {
                const int srow = (mr + r) & 511;
                float sn, cs;
                __sincosf((float)srow * invf, &sn, &cs);
                #pragma unroll
                for (int nip = 0; nip < 2; ++nip) {
                    const int n_lo = bn0 + nip * 128 + jj;
                    const int n_hi = n_lo + 64;
                    const float b_lo = (n_lo < 4096) ? bias0[n_lo]
                                     : (n_lo < 5120) ? bias1[n_lo - 4096] : bias2[n_lo - 5120];
                    const float b_hi = (n_hi < 4096) ? bias0[n_hi]
                                     : (n_hi < 5120) ? bias1[n_hi - 4096] : bias2[n_hi - 5120];
                    const float a_lo = acc[mi][nip * 2][r] + b_lo;
                    const float a_hi = acc[mi][nip * 2 + 1][r] + b_hi;
                    Cb[(size_t)(mr + r) * N + n_lo] = f2bf((a_lo * cs - a_hi * sn) * scale);
                    Cb[(size_t)(mr + r) * N + n_hi] = f2bf((a_hi * cs + a_lo * sn) * scale);
                }
            }
        }
        return;
    }
    #pragma unroll
    for (int mi = 0; mi < 8; ++mi) {
        #pragma unroll
        for (int ni = 0; ni < 4; ++ni) {
            const int n = bn0 + ni * 64 + wc * 16 + lr;
            const float bs = (n < 4096) ? bias0[n]
                           : (n < 5120) ? bias1[n - 4096] : bias2[n - 5120];
            const int mr = bm0 + mi * 32 + wr * 16 + kg * 4;
            #pragma unroll
            for (int r = 0; r < 4; ++r) {
                if (SPLITK) {
                    const int row = mr + r;
                    if (khalf == 0) {
                        Cf[(size_t)row * N + n] = acc[mi][ni][r] + bs;
                    } else {
                        float* P = (row < 1024) ? P0 : P1;
                        P[((size_t)(row & 1023) << 12) + n] = acc[mi][ni][r];
                    }
                } else {
                    const float val = acc[mi][ni][r] + bs;
                    if (OUT_BF16) Cb[(size_t)(mr + r) * N + n] = f2bf(val);
                    else          Cf[(size_t)(mr + r) * N + n] = val;
                }
            }
        }
    }
}

// ---------------- split-K reduce: out += partial (grid-stride) ----------------
__global__ void reduce_add(const float* __restrict__ P0, const float* __restrict__ P1,
                           float* __restrict__ out)
{
    const int n4 = M_ * D_ / 4;
    for (int i4 = blockIdx.x * blockDim.x + threadIdx.x; i4 < n4;
         i4 += gridDim.x * blockDim.x) {
        const float4 p = (i4 < (1 << 20))
            ? *(const float4*)&P0[(size_t)i4 * 4]
            : *(const float4*)&P1[(size_t)(i4 - (1 << 20)) * 4];
        float4 o = *(float4*)&out[(size_t)i4 * 4];
        o.x += p.x; o.y += p.y; o.z += p.z; o.w += p.w;
        *(float4*)&out[(size_t)i4 * 4] = o;
    }
}

// ---------------- V transpose: qkv v-cols -> [B*G][HD][S] ----------------
__global__ __launch_bounds__(256) void vtrans(
    const ushort_t* __restrict__ vb,   // qkv + 5120
    ushort_t* __restrict__ vT)
{
    __shared__ ushort_t t[32][40];
    const int s0 = blockIdx.x * 32;
    const int d0 = blockIdx.y * 32;
    const int bg = blockIdx.z;
    const int b = bg >> 3, g = bg & 7;
    const int tid = threadIdx.x;
    const int row = tid >> 3, c4 = (tid & 7) * 4;
    const us4 v = *(const us4*)&vb[(size_t)(b * S_ + s0 + row) * QN_ + g * HD_ + d0 + c4];
    t[row][c4 + 0] = v.x; t[row][c4 + 1] = v.y;
    t[row][c4 + 2] = v.z; t[row][c4 + 3] = v.w;
    __syncthreads();
    us4 o;
    o.x = t[c4 + 0][row]; o.y = t[c4 + 1][row];
    o.z = t[c4 + 2][row]; o.w = t[c4 + 3][row];
    *(us4*)&vT[(size_t)(bg * HD_ + d0 + row) * S_ + s0 + c4] = o;
}

// ---------------- MFMA attention: block = (b, h, 64 q-rows), 4 waves ----------------
// Double-buffered K/V staging: chunk ch+1's gloads issue before computing ch
// (counted vmcnt(4)); V chunk 0 issues before softmax so the long VALU stretch
// hides its latency.  Ledger: buf written at iter ch was last read at iter
// ch-1, whose phase-end barrier precedes the issue.
__global__ __launch_bounds__(256) void attn_mfma(
    const ushort_t* __restrict__ kb,   // qkv + 4096 (rope'd K cols)
    const ushort_t* __restrict__ vT,   // [B*G][HD][S]
    ushort_t* __restrict__ qb)         // qkv (rope'd+scaled q cols), in/out
{
    __shared__ ushort_t sKV[2][8192];       // 32 KB double-buffered staging
    __shared__ ushort_t sP[4 * 16 * 512];   // 64 KB per-wave P

    const int q0 = blockIdx.x * 64;
    const int h = blockIdx.y, b = blockIdx.z;
    const int g = h >> 2;
    const int tid = threadIdx.x;
    const int lane = tid & 63, w = tid >> 6;
    const int lr = lane & 15, kg = lane >> 4;

    bf16x8 af[4];
    {
        const ushort_t* qrow = qb + (size_t)(b * S_ + q0 + w * 16 + lr) * QN_ + h * HD_;
        #pragma unroll
        for (int c = 0; c < 4; ++c)
            af[c] = *(const bf16x8*)(qrow + c * 32 + kg * 8);
    }

    const ushort_t* kbase = kb + (size_t)b * S_ * QN_ + g * HD_;
    const ushort_t* vbase = vT + (size_t)(b * G_ + g) * HD_ * S_;

    auto kstage = [&](int ch, int buf) {
        #pragma unroll
        for (int i = 0; i < 4; ++i) {
            const int o = w * 4096 + i * 1024;
            const int key = (o >> 8) + (lane >> 4);
            const int sl = lane & 15;
            gload_lds16(kbase + (size_t)(ch * 64 + key) * QN_ + ((sl ^ (key & 15)) * 8),
                        (char*)sKV + buf * 16384 + o);
        }
    };
    auto vstage = [&](int ch, int buf) {
        #pragma unroll
        for (int i = 0; i < 4; ++i) {
            const int o = w * 4096 + i * 1024;
            const int d = (o >> 7) + (lane >> 3);
            const int sl = lane & 7;
            gload_lds16(vbase + (size_t)d * S_ + ch * 64 + ((sl ^ (d & 7)) * 8),
                        (char*)sKV + buf * 16384 + o);
        }
    };

    f32x4 l[8][4];
    #pragma unroll
    for (int ch = 0; ch < 8; ++ch)
        #pragma unroll
        for (int t = 0; t < 4; ++t)
            l[ch][t] = (f32x4){0.f, 0.f, 0.f, 0.f};

    // ---- QK^T: double-buffered ----
    kstage(0, 0);
    #pragma unroll
    for (int ch = 0; ch < 8; ++ch) {
        const int buf = ch & 1;
        if (ch < 7) {
            kstage(ch + 1, buf ^ 1);
            asm volatile("s_waitcnt vmcnt(4)" ::: "memory");
        } else {
            asm volatile("s_waitcnt vmcnt(0)" ::: "memory");
        }
        BAR();
        #pragma unroll
        for (int t = 0; t < 4; ++t) {
            const int key = t * 16 + lr;
            #pragma unroll
            for (int c = 0; c < 4; ++c) {
                const bf16x8 bf = *(const bf16x8*)((const char*)sKV + buf * 16384 +
                                                   key * 256 +
                                                   (((c * 4 + kg) ^ (key & 15)) << 4));
                l[ch][t] = __builtin_amdgcn_mfma_f32_16x16x32_bf16(af[c], bf, l[ch][t], 0, 0, 0);
            }
        }
        BAR();
    }

    // V chunk 0 in flight while softmax runs
    vstage(0, 0);

    // ---- softmax ----
    float inv[4];
    #pragma unroll
    for (int r = 0; r < 4; ++r) {
        float m = -1e30f;
        #pragma unroll
        for (int ch = 0; ch < 8; ++ch)
            #pragma unroll
            for (int t = 0; t < 4; ++t)
                m = fmaxf(m, l[ch][t][r]);
        #pragma unroll
        for (int msk = 1; msk <= 8; msk <<= 1)
            m = fmaxf(m, __shfl_xor(m, msk));
        float s = 0.f;
        const int q = kg * 4 + r;
        #pragma unroll
        for (int ch = 0; ch < 8; ++ch)
            #pragma unroll
            for (int t = 0; t < 4; ++t) {
                const float p = __expf(l[ch][t][r] - m);
                s += p;
                const int gs = ch * 8 + t * 2 + (lr >> 3);
                sP[w * 8192 + q * 512 + ((gs ^ q) << 3) + (lr & 7)] = f2bf(p);
            }
        #pragma unroll
        for (int msk = 1; msk <= 8; msk <<= 1)
            s += __shfl_xor(s, msk);
        inv[r] = 1.f / s;
    }

    // ---- PV: double-buffered ----
    f32x4 oacc[8];
    #pragma unroll
    for (int dt = 0; dt < 8; ++dt) oacc[dt] = (f32x4){0.f, 0.f, 0.f, 0.f};

    #pragma unroll
    for (int ch = 0; ch < 8; ++ch) {
        const int buf = ch & 1;
        if (ch < 7) {
            vstage(ch + 1, buf ^ 1);
            asm volatile("s_waitcnt vmcnt(4)" ::: "memory");
        } else {
            asm volatile("s_waitcnt vmcnt(0)" ::: "memory");
        }
        BAR();
        #pragma unroll
        for (int c2 = 0; c2 < 2; ++c2) {
            const int gs = ch * 8 + c2 * 4 + kg;
            const bf16x8 ap = *(const bf16x8*)((const char*)sP + w * 16384 + lr * 1024 +
                                               ((gs ^ lr) << 4));
            #pragma unroll
            for (int dt = 0; dt < 8; ++dt) {
                const int d = dt * 16 + lr;
                const bf16x8 bv = *(const bf16x8*)((const char*)sKV + buf * 16384 +
                                                   d * 128 +
                                                   (((c2 * 4 + kg) ^ (d & 7)) << 4));
                oacc[dt] = __builtin_amdgcn_mfma_f32_16x16x32_bf16(ap, bv, oacc[dt], 0, 0, 0);
            }
        }
        BAR();
    }

    #pragma unroll
    for (int dt = 0; dt < 8; ++dt) {
        #pragma unroll
        for (int r = 0; r < 4; ++r) {
            const int q = kg * 4 + r;
            qb[(size_t)(b * S_ + q0 + w * 16 + q) * QN_ + h * HD_ + dt * 16 + lr] =
                f2bf(oacc[dt][r] * inv[r]);
        }
    }
}

extern "C" void kernel_launch(void* const* d_in, const int* in_sizes, int n_in,
                              void* d_out, int out_size, void* d_ws, size_t ws_size,
                              hipStream_t stream)
{
    const float* x  = (const float*)d_in[0];
    const float* wq = (const float*)d_in[1];
    const float* bq = (const float*)d_in[2];
    const float* wk = (const float*)d_in[3];
    const float* bk = (const float*)d_in[4];
    const float* wv = (const float*)d_in[5];
    const float* bv = (const float*)d_in[6];
    const float* wo = (const float*)d_in[7];
    const float* bo = (const float*)d_in[8];
    float* out = (float*)d_out;

    char* ws = (char*)d_ws;
    ushort_t* xb   = (ushort_t*)(ws);                 // 16 MB: x bf16; later splitK P0
    ushort_t* Wt   = (ushort_t*)(ws + (16u << 20));   // 48 MB: wq|wk|wv; later wo rows 0-4095
    ushort_t* vT   = (ushort_t*)(ws + (48u << 20));   //  4 MB: dead wk rows after QKV GEMM
    ushort_t* qkv  = (ushort_t*)(ws + (64u << 20));   // 24 MB: [2048][6144] bf16
    float* p0      = (float*)xb;                      // 16 MB fp32 (xb dead post-QKV)
    float* p1      = (float*)(ws + (48u << 20));      // 16 MB fp32 (post-attn)
    // total 88 MB

    // weights first, x last -> QKV GEMM inputs are the freshest L3 stream
    wconv_all<<<dim3(QN_ / 32, D_ / 32), 256, 0, stream>>>(wq, wk, wv, Wt);
    xconv<<<(M_ * D_ / 8 + 255) / 256, 256, 0, stream>>>(x, xb, M_ * D_ / 8);

    // fused QKV projection + RoPE + q-scale in epilogue: [2048][6144]
    gemm8<1, 0, 1><<<(QN_ / 256) * (M_ / 256), 512, 0, stream>>>(
        xb, D_, Wt, D_, bq, bk, bv, nullptr, qkv, nullptr, nullptr, M_, QN_, D_);

    vtrans<<<dim3(S_ / 32, HD_ / 32, B_ * G_), 256, 0, stream>>>(qkv + 5120, vT);

    attn_mfma<<<dim3(S_ / 64, H_, B_), 256, 0, stream>>>(qkv + 4096, vT, qkv);

    // wo -> rows 0-4095 of Wt (wq part is dead now)
    wconv<<<dim3(D_ / 32, D_ / 32), 256, 0, stream>>>(wo, Wt, D_, D_);

    // O projection, split-K=2 across a full 256-block grid
    gemm8<0, 1, 0><<<256, 512, 0, stream>>>(
        qkv, QN_, Wt, D_, bo, bo, bo, out, nullptr, p0, p1, M_, D_, 2048);
    reduce_add<<<2048, 256, 0, stream>>>(p0, p1, out);
}

// Round 12
// 312.627 us; speedup vs baseline: 1.0475x; 1.0475x over previous
//
#include <hip/hip_runtime.h>
#include <math.h>

typedef unsigned short ushort_t;
typedef __attribute__((ext_vector_type(8))) short bf16x8;
typedef __attribute__((ext_vector_type(4))) float f32x4;
typedef __attribute__((ext_vector_type(4))) unsigned short us4;
typedef __attribute__((ext_vector_type(8))) unsigned short us8;

#define B_   4
#define S_   512
#define D_   4096
#define H_   32
#define G_   8
#define HD_  128
#define KV_  1024
#define M_   (B_ * S_)   // 2048
#define QN_  6144        // fused QKV column count

__device__ __forceinline__ float bf2f(ushort_t u) {
    union { unsigned u; float f; } x; x.u = ((unsigned)u) << 16; return x.f;
}
__device__ __forceinline__ ushort_t f2bf(float f) {
    union { float f; unsigned u; } x; x.f = f;
    unsigned r = x.u + 0x7fffu + ((x.u >> 16) & 1u);   // round-to-nearest-even
    return (ushort_t)(r >> 16);
}

typedef const __attribute__((address_space(1))) void* gptr_t;
typedef __attribute__((address_space(3))) void* ldsptr_t;

__device__ __forceinline__ void gload_lds16(const void* g, void* lds) {
    __builtin_amdgcn_global_load_lds((gptr_t)g, (ldsptr_t)lds, 16, 0, 0);
}

#define BAR() asm volatile("s_barrier" ::: "memory")

// ---------------- fp32 -> bf16 elementwise ----------------
__global__ void xconv(const float* __restrict__ x, ushort_t* __restrict__ xb, int n8)
{
    const int i = blockIdx.x * blockDim.x + threadIdx.x;
    if (i >= n8) return;
    const float4 a = *(const float4*)&x[(size_t)i * 8];
    const float4 b = *(const float4*)&x[(size_t)i * 8 + 4];
    us8 o;
    o[0] = f2bf(a.x); o[1] = f2bf(a.y); o[2] = f2bf(a.z); o[3] = f2bf(a.w);
    o[4] = f2bf(b.x); o[5] = f2bf(b.y); o[6] = f2bf(b.z); o[7] = f2bf(b.w);
    *(us8*)&xb[(size_t)i * 8] = o;
}

// ------- fused W transpose: {wq|wk|wv} [4096][N] fp32 -> Wt [6144][4096] bf16 -------
__global__ __launch_bounds__(256) void wconv_all(
    const float* __restrict__ wq, const float* __restrict__ wk,
    const float* __restrict__ wv, ushort_t* __restrict__ Wt)
{
    __shared__ float t[32][33];
    const int n0 = blockIdx.x * 32, k0 = blockIdx.y * 32;
    const float* W; int nsrc, N;
    if (n0 < 4096)      { W = wq; nsrc = n0;        N = 4096; }
    else if (n0 < 5120) { W = wk; nsrc = n0 - 4096; N = 1024; }
    else                { W = wv; nsrc = n0 - 5120; N = 1024; }
    const int tid = threadIdx.x;
    const int r = tid >> 3, c4 = (tid & 7) * 4;
    const float4 v = *(const float4*)&W[(size_t)(k0 + r) * N + nsrc + c4];
    t[r][c4 + 0] = v.x; t[r][c4 + 1] = v.y; t[r][c4 + 2] = v.z; t[r][c4 + 3] = v.w;
    __syncthreads();
    us4 o;
    o.x = f2bf(t[c4 + 0][r]);
    o.y = f2bf(t[c4 + 1][r]);
    o.z = f2bf(t[c4 + 2][r]);
    o.w = f2bf(t[c4 + 3][r]);
    *(us4*)&Wt[(size_t)(n0 + r) * D_ + k0 + c4] = o;
}

// ---------------- W [K][N] fp32 -> Wt [N][K] bf16 (single, for wo) ----------------
__global__ __launch_bounds__(256) void wconv(
    const float* __restrict__ W, ushort_t* __restrict__ Wt, int K, int N)
{
    __shared__ float t[32][33];
    const int n0 = blockIdx.x * 32, k0 = blockIdx.y * 32;
    const int tid = threadIdx.x;
    const int r = tid >> 3, c4 = (tid & 7) * 4;
    const float4 v = *(const float4*)&W[(size_t)(k0 + r) * N + n0 + c4];
    t[r][c4 + 0] = v.x; t[r][c4 + 1] = v.y; t[r][c4 + 2] = v.z; t[r][c4 + 3] = v.w;
    __syncthreads();
    us4 o;
    o.x = f2bf(t[c4 + 0][r]);
    o.y = f2bf(t[c4 + 1][r]);
    o.z = f2bf(t[c4 + 2][r]);
    o.w = f2bf(t[c4 + 3][r]);
    *(us4*)&Wt[(size_t)(n0 + r) * K + k0 + c4] = o;
}

// ============ 256x256 8-phase MFMA GEMM (T1+T2+T3+T4+T5) ============
// C[M,N] = A[M,K] @ Bt[N,K]^T + bias.  BK=64, 8 waves (2M x 4N).
// Staging addresses precomputed per-thread (8 pointers, advance t*64 elems);
// K-loop unrolled x2 with LDS buffer index c as a per-copy literal (round-11,
// QKV 129 -> 125.5 us).  Sync structure = proven round-8 form.
template<int OUT_BF16, int SPLITK, int ROPE>
__global__ __launch_bounds__(512, 2) void gemm8(
    const ushort_t* __restrict__ A, int lda,
    const ushort_t* __restrict__ Bt, int ldb,
    const float* __restrict__ bias0, const float* __restrict__ bias1,
    const float* __restrict__ bias2,
    float* __restrict__ Cf, ushort_t* __restrict__ Cb,
    float* __restrict__ P0, float* __restrict__ P1,
    int M, int N, int K)
{
    __shared__ ushort_t sA[2][256 * 64];   // 64 KiB
    __shared__ ushort_t sB[2][256 * 64];   // 64 KiB

    const int tid = threadIdx.x;
    const int lane = tid & 63, w = tid >> 6;
    const int lr = lane & 15, kg = lane >> 4;
    const int wr = w >> 2, wc = w & 3;

    // T1: XCD-aware swizzle (grids here are multiples of 8)
    const int nwg = gridDim.x;
    const int cpx = nwg >> 3;
    const int bid = (blockIdx.x & 7) * cpx + (blockIdx.x >> 3);
    int khalf = 0, tile = bid;
    if (SPLITK) { khalf = bid >> 7; tile = bid & 127; }
    const int nbx = N >> 8;
    const int bx = tile % nbx, by = tile / nbx;
    const int bm0 = by << 8, bn0 = bx << 8;
    if (SPLITK) { A += (size_t)khalf * K; Bt += (size_t)khalf * K; }

    const int NT = K >> 6;

    // Precomputed staging pointers: half h (0=A-lo 1=A-hi 2=B-lo 3=B-hi), j=0,1
    const ushort_t* gp[4][2];
    char*           lp[4][2];
    #pragma unroll
    for (int h = 0; h < 4; ++h) {
        const ushort_t* gb; int ld; char* sbase;
        if (h < 2) { gb = A + (size_t)bm0 * lda; ld = lda; sbase = (char*)sA; }
        else       { gb = Bt + (size_t)bn0 * ldb; ld = ldb; sbase = (char*)sB; }
        const int half = h & 1;
        #pragma unroll
        for (int j = 0; j < 2; ++j) {
            const int o = j * 8192 + tid * 16;       // byte within 16KB half
            const int row = half * 128 + (o >> 7);   // tile row
            const int slot = (o >> 4) & 7;
            gp[h][j] = gb + (size_t)row * ld + ((slot ^ (row & 7)) << 3);
            lp[h][j] = sbase + half * 16384 + j * 8192 + w * 1024;
        }
    }
    auto stage = [&](int t, int h, int c) {
        #pragma unroll
        for (int j = 0; j < 2; ++j)
            gload_lds16(gp[h][j] + t * 64, lp[h][j] + c * 32768);
    };
    auto lda_frag = [&](int c, int mi, int s) {
        const int row = mi * 32 + wr * 16 + lr;
        return *(const bf16x8*)((const char*)sA + c * 32768 + row * 128 +
                                (((s * 4 + kg) ^ (row & 7)) << 4));
    };
    auto ldb_frag = [&](int c, int ni, int s) {
        const int row = ni * 64 + wc * 16 + lr;
        return *(const bf16x8*)((const char*)sB + c * 32768 + row * 128 +
                                (((s * 4 + kg) ^ (row & 7)) << 4));
    };

    f32x4 acc[8][4];
    #pragma unroll
    for (int i = 0; i < 8; ++i)
        #pragma unroll
        for (int j = 0; j < 4; ++j)
            acc[i][j] = (f32x4){0.f, 0.f, 0.f, 0.f};

    // prologue: 7 halves in flight, confirm tile 0 (vmcnt 6 = 3 halves out)
    stage(0, 0, 0); stage(0, 2, 0); stage(0, 3, 0); stage(0, 1, 0);
    stage(1, 0, 1); stage(1, 2, 1); stage(1, 3, 1);
    asm volatile("s_waitcnt vmcnt(6)" ::: "memory");
    BAR();

    auto iter = [&](int t, int c) {
        bf16x8 a[4][2], b[4][2];

        // ---- P1: quad (0,0): A-lo x B-lo ----
        #pragma unroll
        for (int ni = 0; ni < 2; ++ni)
            #pragma unroll
            for (int s = 0; s < 2; ++s) b[ni][s] = ldb_frag(c, ni, s);
        #pragma unroll
        for (int mi = 0; mi < 4; ++mi)
            #pragma unroll
            for (int s = 0; s < 2; ++s) a[mi][s] = lda_frag(c, mi, s);
        if (t + 1 < NT) stage(t + 1, 1, c ^ 1);
        BAR();
        __builtin_amdgcn_s_setprio(1);
        #pragma unroll
        for (int mi = 0; mi < 4; ++mi)
            #pragma unroll
            for (int ni = 0; ni < 2; ++ni)
                #pragma unroll
                for (int s = 0; s < 2; ++s)
                    acc[mi][ni] = __builtin_amdgcn_mfma_f32_16x16x32_bf16(
                        a[mi][s], b[ni][s], acc[mi][ni], 0, 0, 0);
        __builtin_amdgcn_s_setprio(0);
        BAR();

        // ---- P2: quad (0,1): A-lo x B-hi ----
        #pragma unroll
        for (int ni = 2; ni < 4; ++ni)
            #pragma unroll
            for (int s = 0; s < 2; ++s) b[ni][s] = ldb_frag(c, ni, s);
        if (t + 2 < NT) stage(t + 2, 0, c);
        BAR();
        __builtin_amdgcn_s_setprio(1);
        #pragma unroll
        for (int mi = 0; mi < 4; ++mi)
            #pragma unroll
            for (int ni = 2; ni < 4; ++ni)
                #pragma unroll
                for (int s = 0; s < 2; ++s)
                    acc[mi][ni] = __builtin_amdgcn_mfma_f32_16x16x32_bf16(
                        a[mi][s], b[ni][s], acc[mi][ni], 0, 0, 0);
        __builtin_amdgcn_s_setprio(0);
        BAR();

        // ---- P3: quad (1,1): A-hi x B-hi ----
        #pragma unroll
        for (int mi = 0; mi < 4; ++mi)
            #pragma unroll
            for (int s = 0; s < 2; ++s) a[mi][s] = lda_frag(c, mi + 4, s);
        if (t + 2 < NT) stage(t + 2, 2, c);
        BAR();
        __builtin_amdgcn_s_setprio(1);
        #pragma unroll
        for (int mi = 0; mi < 4; ++mi)
            #pragma unroll
            for (int ni = 2; ni < 4; ++ni)
                #pragma unroll
                for (int s = 0; s < 2; ++s)
                    acc[mi + 4][ni] = __builtin_amdgcn_mfma_f32_16x16x32_bf16(
                        a[mi][s], b[ni][s], acc[mi + 4][ni], 0, 0, 0);
        __builtin_amdgcn_s_setprio(0);
        BAR();

        // ---- P4: quad (1,0): A-hi x B-lo ----
        if (t + 2 < NT) {
            stage(t + 2, 3, c);
            asm volatile("s_waitcnt vmcnt(6)" ::: "memory");
        } else {
            asm volatile("s_waitcnt vmcnt(0)" ::: "memory");
        }
        BAR();
        __builtin_amdgcn_s_setprio(1);
        #pragma unroll
        for (int mi = 0; mi < 4; ++mi)
            #pragma unroll
            for (int ni = 0; ni < 2; ++ni)
                #pragma unroll
                for (int s = 0; s < 2; ++s)
                    acc[mi + 4][ni] = __builtin_amdgcn_mfma_f32_16x16x32_bf16(
                        a[mi][s], b[ni][s], acc[mi + 4][ni], 0, 0, 0);
        __builtin_amdgcn_s_setprio(0);
        BAR();
    };

    for (int t = 0; t < NT; t += 2) { iter(t, 0); iter(t + 1, 1); }

    // ---- epilogue ----
    if (ROPE && bn0 < 5120) {
        const float scale = (bn0 < 4096) ? (1.f / 128.f) : 1.f;
        const int jj = wc * 16 + lr;                                 // n & 63
        const float invf = __expf(-0.1439115683121279f * (float)jj); // 10000^(-jj/64)
        #pragma unroll
        for (int mi = 0; mi < 8; ++mi) {
            const int mr = bm0 + mi * 32 + wr * 16 + kg * 4;
            #pragma unroll
            for (int r = 0; r < 4; ++r) {
                const int srow = (mr + r) & 511;
                float sn, cs;
                __sincosf((float)srow * invf, &sn, &cs);
                #pragma unroll
                for (int nip = 0; nip < 2; ++nip) {
                    const int n_lo = bn0 + nip * 128 + jj;
                    const int n_hi = n_lo + 64;
                    const float b_lo = (n_lo < 4096) ? bias0[n_lo]
                                     : (n_lo < 5120) ? bias1[n_lo - 4096] : bias2[n_lo - 5120];
                    const float b_hi = (n_hi < 4096) ? bias0[n_hi]
                                     : (n_hi < 5120) ? bias1[n_hi - 4096] : bias2[n_hi - 5120];
                    const float a_lo = acc[mi][nip * 2][r] + b_lo;
                    const float a_hi = acc[mi][nip * 2 + 1][r] + b_hi;
                    Cb[(size_t)(mr + r) * N + n_lo] = f2bf((a_lo * cs - a_hi * sn) * scale);
                    Cb[(size_t)(mr + r) * N + n_hi] = f2bf((a_hi * cs + a_lo * sn) * scale);
                }
            }
        }
        return;
    }
    #pragma unroll
    for (int mi = 0; mi < 8; ++mi) {
        #pragma unroll
        for (int ni = 0; ni < 4; ++ni) {
            const int n = bn0 + ni * 64 + wc * 16 + lr;
            const float bs = (n < 4096) ? bias0[n]
                           : (n < 5120) ? bias1[n - 4096] : bias2[n - 5120];
            const int mr = bm0 + mi * 32 + wr * 16 + kg * 4;
            #pragma unroll
            for (int r = 0; r < 4; ++r) {
                if (SPLITK) {
                    const int row = mr + r;
                    if (khalf == 0) {
                        Cf[(size_t)row * N + n] = acc[mi][ni][r] + bs;
                    } else {
                        float* P = (row < 1024) ? P0 : P1;
                        P[((size_t)(row & 1023) << 12) + n] = acc[mi][ni][r];
                    }
                } else {
                    const float val = acc[mi][ni][r] + bs;
                    if (OUT_BF16) Cb[(size_t)(mr + r) * N + n] = f2bf(val);
                    else          Cf[(size_t)(mr + r) * N + n] = val;
                }
            }
        }
    }
}

// ---------------- split-K reduce: out += partial (grid-stride) ----------------
__global__ void reduce_add(const float* __restrict__ P0, const float* __restrict__ P1,
                           float* __restrict__ out)
{
    const int n4 = M_ * D_ / 4;
    for (int i4 = blockIdx.x * blockDim.x + threadIdx.x; i4 < n4;
         i4 += gridDim.x * blockDim.x) {
        const float4 p = (i4 < (1 << 20))
            ? *(const float4*)&P0[(size_t)i4 * 4]
            : *(const float4*)&P1[(size_t)(i4 - (1 << 20)) * 4];
        float4 o = *(float4*)&out[(size_t)i4 * 4];
        o.x += p.x; o.y += p.y; o.z += p.z; o.w += p.w;
        *(float4*)&out[(size_t)i4 * 4] = o;
    }
}

// ---------------- V transpose: qkv v-cols -> [B*G][HD][S] ----------------
__global__ __launch_bounds__(256) void vtrans(
    const ushort_t* __restrict__ vb,   // qkv + 5120
    ushort_t* __restrict__ vT)
{
    __shared__ ushort_t t[32][40];
    const int s0 = blockIdx.x * 32;
    const int d0 = blockIdx.y * 32;
    const int bg = blockIdx.z;
    const int b = bg >> 3, g = bg & 7;
    const int tid = threadIdx.x;
    const int row = tid >> 3, c4 = (tid & 7) * 4;
    const us4 v = *(const us4*)&vb[(size_t)(b * S_ + s0 + row) * QN_ + g * HD_ + d0 + c4];
    t[row][c4 + 0] = v.x; t[row][c4 + 1] = v.y;
    t[row][c4 + 2] = v.z; t[row][c4 + 3] = v.w;
    __syncthreads();
    us4 o;
    o.x = t[c4 + 0][row]; o.y = t[c4 + 1][row];
    o.z = t[c4 + 2][row]; o.w = t[c4 + 3][row];
    *(us4*)&vT[(size_t)(bg * HD_ + d0 + row) * S_ + s0 + c4] = o;
}

// ---------------- MFMA attention: block = (b, h, 64 q-rows), 4 waves ----------------
// Single-buffer staging (80 KB LDS -> 2 blocks/CU).  Round-11 dbuf (96 KB)
// dropped occupancy to 1 block/CU and cost +18us: inter-block TLP was the
// latency hiding, keep it.
__global__ __launch_bounds__(256) void attn_mfma(
    const ushort_t* __restrict__ kb,   // qkv + 4096 (rope'd K cols)
    const ushort_t* __restrict__ vT,   // [B*G][HD][S]
    ushort_t* __restrict__ qb)         // qkv (rope'd+scaled q cols), in/out
{
    __shared__ ushort_t sKV[8192];          // 16 KB staging
    __shared__ ushort_t sP[4 * 16 * 512];   // 64 KB per-wave P

    const int q0 = blockIdx.x * 64;
    const int h = blockIdx.y, b = blockIdx.z;
    const int g = h >> 2;
    const int tid = threadIdx.x;
    const int lane = tid & 63, w = tid >> 6;
    const int lr = lane & 15, kg = lane >> 4;

    bf16x8 af[4];
    {
        const ushort_t* qrow = qb + (size_t)(b * S_ + q0 + w * 16 + lr) * QN_ + h * HD_;
        #pragma unroll
        for (int c = 0; c < 4; ++c)
            af[c] = *(const bf16x8*)(qrow + c * 32 + kg * 8);
    }

    f32x4 l[8][4];
    #pragma unroll
    for (int ch = 0; ch < 8; ++ch)
        #pragma unroll
        for (int t = 0; t < 4; ++t)
            l[ch][t] = (f32x4){0.f, 0.f, 0.f, 0.f};

    // ---- QK^T ----
    const ushort_t* kbase = kb + (size_t)b * S_ * QN_ + g * HD_;
    #pragma unroll
    for (int ch = 0; ch < 8; ++ch) {
        __syncthreads();
        #pragma unroll
        for (int i = 0; i < 4; ++i) {
            const int o = w * 4096 + i * 1024;
            const int key = (o >> 8) + (lane >> 4);
            const int sl = lane & 15;
            gload_lds16(kbase + (size_t)(ch * 64 + key) * QN_ + ((sl ^ (key & 15)) * 8),
                        (char*)sKV + o);
        }
        __syncthreads();
        #pragma unroll
        for (int t = 0; t < 4; ++t) {
            const int key = t * 16 + lr;
            #pragma unroll
            for (int c = 0; c < 4; ++c) {
                const bf16x8 bf = *(const bf16x8*)((const char*)sKV + key * 256 +
                                                   (((c * 4 + kg) ^ (key & 15)) << 4));
                l[ch][t] = __builtin_amdgcn_mfma_f32_16x16x32_bf16(af[c], bf, l[ch][t], 0, 0, 0);
            }
        }
    }

    // ---- softmax ----
    float inv[4];
    #pragma unroll
    for (int r = 0; r < 4; ++r) {
        float m = -1e30f;
        #pragma unroll
        for (int ch = 0; ch < 8; ++ch)
            #pragma unroll
            for (int t = 0; t < 4; ++t)
                m = fmaxf(m, l[ch][t][r]);
        #pragma unroll
        for (int msk = 1; msk <= 8; msk <<= 1)
            m = fmaxf(m, __shfl_xor(m, msk));
        float s = 0.f;
        const int q = kg * 4 + r;
        #pragma unroll
        for (int ch = 0; ch < 8; ++ch)
            #pragma unroll
            for (int t = 0; t < 4; ++t) {
                const float p = __expf(l[ch][t][r] - m);
                s += p;
                const int gs = ch * 8 + t * 2 + (lr >> 3);
                sP[w * 8192 + q * 512 + ((gs ^ q) << 3) + (lr & 7)] = f2bf(p);
            }
        #pragma unroll
        for (int msk = 1; msk <= 8; msk <<= 1)
            s += __shfl_xor(s, msk);
        inv[r] = 1.f / s;
    }

    // ---- PV ----
    f32x4 oacc[8];
    #pragma unroll
    for (int dt = 0; dt < 8; ++dt) oacc[dt] = (f32x4){0.f, 0.f, 0.f, 0.f};

    const ushort_t* vbase = vT + (size_t)(b * G_ + g) * HD_ * S_;
    for (int ch = 0; ch < 8; ++ch) {
        __syncthreads();
        #pragma unroll
        for (int i = 0; i < 4; ++i) {
            const int o = w * 4096 + i * 1024;
            const int d = (o >> 7) + (lane >> 3);
            const int sl = lane & 7;
            gload_lds16(vbase + (size_t)d * S_ + ch * 64 + ((sl ^ (d & 7)) * 8),
                        (char*)sKV + o);
        }
        __syncthreads();
        #pragma unroll
        for (int c2 = 0; c2 < 2; ++c2) {
            const int gs = ch * 8 + c2 * 4 + kg;
            const bf16x8 ap = *(const bf16x8*)((const char*)sP + w * 16384 + lr * 1024 +
                                               ((gs ^ lr) << 4));
            #pragma unroll
            for (int dt = 0; dt < 8; ++dt) {
                const int d = dt * 16 + lr;
                const bf16x8 bv = *(const bf16x8*)((const char*)sKV + d * 128 +
                                                   (((c2 * 4 + kg) ^ (d & 7)) << 4));
                oacc[dt] = __builtin_amdgcn_mfma_f32_16x16x32_bf16(ap, bv, oacc[dt], 0, 0, 0);
            }
        }
    }

    #pragma unroll
    for (int dt = 0; dt < 8; ++dt) {
        #pragma unroll
        for (int r = 0; r < 4; ++r) {
            const int q = kg * 4 + r;
            qb[(size_t)(b * S_ + q0 + w * 16 + q) * QN_ + h * HD_ + dt * 16 + lr] =
                f2bf(oacc[dt][r] * inv[r]);
        }
    }
}

extern "C" void kernel_launch(void* const* d_in, const int* in_sizes, int n_in,
                              void* d_out, int out_size, void* d_ws, size_t ws_size,
                              hipStream_t stream)
{
    const float* x  = (const float*)d_in[0];
    const float* wq = (const float*)d_in[1];
    const float* bq = (const float*)d_in[2];
    const float* wk = (const float*)d_in[3];
    const float* bk = (const float*)d_in[4];
    const float* wv = (const float*)d_in[5];
    const float* bv = (const float*)d_in[6];
    const float* wo = (const float*)d_in[7];
    const float* bo = (const float*)d_in[8];
    float* out = (float*)d_out;

    char* ws = (char*)d_ws;
    ushort_t* xb   = (ushort_t*)(ws);                 // 16 MB: x bf16; later splitK P0
    ushort_t* Wt   = (ushort_t*)(ws + (16u << 20));   // 48 MB: wq|wk|wv; later wo rows 0-4095
    ushort_t* vT   = (ushort_t*)(ws + (48u << 20));   //  4 MB: dead wk rows after QKV GEMM
    ushort_t* qkv  = (ushort_t*)(ws + (64u << 20));   // 24 MB: [2048][6144] bf16
    float* p0      = (float*)xb;                      // 16 MB fp32 (xb dead post-QKV)
    float* p1      = (float*)(ws + (48u << 20));      // 16 MB fp32 (post-attn)
    // total 88 MB

    // weights first, x last -> QKV GEMM inputs are the freshest L3 stream
    wconv_all<<<dim3(QN_ / 32, D_ / 32), 256, 0, stream>>>(wq, wk, wv, Wt);
    xconv<<<(M_ * D_ / 8 + 255) / 256, 256, 0, stream>>>(x, xb, M_ * D_ / 8);

    // fused QKV projection + RoPE + q-scale in epilogue: [2048][6144]
    gemm8<1, 0, 1><<<(QN_ / 256) * (M_ / 256), 512, 0, stream>>>(
        xb, D_, Wt, D_, bq, bk, bv, nullptr, qkv, nullptr, nullptr, M_, QN_, D_);

    vtrans<<<dim3(S_ / 32, HD_ / 32, B_ * G_), 256, 0, stream>>>(qkv + 5120, vT);

    attn_mfma<<<dim3(S_ / 64, H_, B_), 256, 0, stream>>>(qkv + 4096, vT, qkv);

    // wo -> rows 0-4095 of Wt (wq part is dead now)
    wconv<<<dim3(D_ / 32, D_ / 32), 256, 0, stream>>>(wo, Wt, D_, D_);

    // O projection, split-K=2 across a full 256-block grid
    gemm8<0, 1, 0><<<256, 512, 0, stream>>>(
        qkv, QN_, Wt, D_, bo, bo, bo, out, nullptr, p0, p1, M_, D_, 2048);
    reduce_add<<<2048, 256, 0, stream>>>(p0, p1, out);
}